// Round 1
// baseline (875.469 us; speedup 1.0000x reference)
//
#include <hip/hip_runtime.h>
#include <math.h>

#define NLEVELS 16
#define LOG2_T 19
#define TSIZE (1u << LOG2_T)
#define TMASK (TSIZE - 1u)
#define NPTS 1048576

typedef float vfloat2 __attribute__((ext_vector_type(2)));
typedef float vfloat4 __attribute__((ext_vector_type(4)));

struct Res16 { float r[NLEVELS]; };

// 2D grid: blockIdx.y = level, blockIdx.x = point block (256 pts).
// HIP dispatches x-fastest -> all blocks of level 0 first, etc. => temporal
// level phasing: each XCD's 4 MiB L2 holds the one active 4 MiB level slice.
//
// Gather-pairing trick (this round): P1 == 1, so for even ix the corner pair
// (dx=0, dx=1) hashes to adjacent table entries (h ^ 1) inside one aligned
// 16 B quad. Load the quad once with dwordx4 and select both corners from it;
// only odd-ix lanes issue the 4 extra dx=1 gathers (exec-masked). Cuts the
// per-lane unique-address work of the divergent-gather pipeline from 8 to ~6.
__global__ __launch_bounds__(256) void HashGridEncoder_68925635166659_kernel(
    const float* __restrict__ x,
    const vfloat2* __restrict__ table,
    vfloat2* __restrict__ out,
    Res16 res)
{
    const int l = blockIdx.y;
    const int n = blockIdx.x * blockDim.x + threadIdx.x;

    const float px = __builtin_nontemporal_load(x + 3 * n + 0);
    const float py = __builtin_nontemporal_load(x + 3 * n + 1);
    const float pz = __builtin_nontemporal_load(x + 3 * n + 2);
    const float r  = res.r[l];

    // Match reference f32 ops exactly: mul, floor, sub.
    const float sx = px * r, sy = py * r, sz = pz * r;
    const float fx = floorf(sx), fy = floorf(sy), fz = floorf(sz);
    const float wx = sx - fx, wy = sy - fy, wz = sz - fz;

    const uint32_t ix = (uint32_t)(int)fx;
    const uint32_t iy = (uint32_t)(int)fy;
    const uint32_t iz = (uint32_t)(int)fz;

    // h = ix*P1 ^ iy*P2 ^ iz*P3  (uint32 wrap == numpy uint32)
    const uint32_t hx0 = ix;                         // P1 = 1
    const uint32_t hx1 = ix + 1u;
    const uint32_t hy0 = iy * 2654435761u;
    const uint32_t hy1 = hy0 + 2654435761u;          // (iy+1)*P2 mod 2^32
    const uint32_t hz0 = iz * 805459861u;
    const uint32_t hz1 = hz0 + 805459861u;

    const vfloat2* __restrict__ tl  = table + (uint32_t)l * TSIZE;
    const vfloat4* __restrict__ tl4 = (const vfloat4*)tl;   // aligned entry pairs

    // dx=0 corner indices (masked); bit0 survives the mask.
    const uint32_t b000 = (hx0 ^ hy0 ^ hz0) & TMASK;
    const uint32_t b001 = (hx0 ^ hy0 ^ hz1) & TMASK;
    const uint32_t b010 = (hx0 ^ hy1 ^ hz0) & TMASK;
    const uint32_t b011 = (hx0 ^ hy1 ^ hz1) & TMASK;

    // One 16 B quad per (dy,dz) combo covers entries {b & ~1, b | 1}.
    const vfloat4 q00 = tl4[b000 >> 1];
    const vfloat4 q01 = tl4[b001 >> 1];
    const vfloat4 q10 = tl4[b010 >> 1];
    const vfloat4 q11 = tl4[b011 >> 1];

    // dx=0 corner = the half addressed by b; other half = dx=1 corner iff ix even.
    const vfloat2 c000 = (b000 & 1u) ? vfloat2{q00.z, q00.w} : vfloat2{q00.x, q00.y};
    const vfloat2 c001 = (b001 & 1u) ? vfloat2{q01.z, q01.w} : vfloat2{q01.x, q01.y};
    const vfloat2 c010 = (b010 & 1u) ? vfloat2{q10.z, q10.w} : vfloat2{q10.x, q10.y};
    const vfloat2 c011 = (b011 & 1u) ? vfloat2{q11.z, q11.w} : vfloat2{q11.x, q11.y};

    vfloat2 c100 = (b000 & 1u) ? vfloat2{q00.x, q00.y} : vfloat2{q00.z, q00.w};
    vfloat2 c101 = (b001 & 1u) ? vfloat2{q01.x, q01.y} : vfloat2{q01.z, q01.w};
    vfloat2 c110 = (b010 & 1u) ? vfloat2{q10.x, q10.y} : vfloat2{q10.z, q10.w};
    vfloat2 c111 = (b011 & 1u) ? vfloat2{q11.x, q11.y} : vfloat2{q11.z, q11.w};

    if (ix & 1u) {
        // Carry propagated: (ix+1) differs from ix beyond bit0 -> real gathers,
        // issued only by odd-ix lanes (exec mask), ~half the wave on average.
        c100 = tl[(hx1 ^ hy0 ^ hz0) & TMASK];
        c101 = tl[(hx1 ^ hy0 ^ hz1) & TMASK];
        c110 = tl[(hx1 ^ hy1 ^ hz0) & TMASK];
        c111 = tl[(hx1 ^ hy1 ^ hz1) & TMASK];
    }

    const float wx0 = 1.0f - wx, wy0 = 1.0f - wy, wz0 = 1.0f - wz;

    float f0 = 0.0f, f1 = 0.0f;
    float w;
    // Same corner order as reference loop (dz innermost).
    w = (wx0 * wy0) * wz0; f0 += c000.x * w; f1 += c000.y * w;
    w = (wx0 * wy0) * wz;  f0 += c001.x * w; f1 += c001.y * w;
    w = (wx0 * wy ) * wz0; f0 += c010.x * w; f1 += c010.y * w;
    w = (wx0 * wy ) * wz;  f0 += c011.x * w; f1 += c011.y * w;
    w = (wx  * wy0) * wz0; f0 += c100.x * w; f1 += c100.y * w;
    w = (wx  * wy0) * wz;  f0 += c101.x * w; f1 += c101.y * w;
    w = (wx  * wy ) * wz0; f0 += c110.x * w; f1 += c110.y * w;
    w = (wx  * wy ) * wz;  f0 += c111.x * w; f1 += c111.y * w;

    vfloat2 v; v.x = f0; v.y = f1;
    __builtin_nontemporal_store(v, out + (uint32_t)n * NLEVELS + (uint32_t)l);
}

extern "C" void kernel_launch(void* const* d_in, const int* in_sizes, int n_in,
                              void* d_out, int out_size, void* d_ws, size_t ws_size,
                              hipStream_t stream) {
    const float*   x     = (const float*)d_in[0];
    const vfloat2* table = (const vfloat2*)d_in[1];
    vfloat2*       out   = (vfloat2*)d_out;

    // Exact numpy recipe in double: floor(16 * growth^l), growth = exp(ln(256)/15)
    Res16 res;
    const double growth = exp((log(4096.0) - log(16.0)) / 15.0);
    for (int l = 0; l < NLEVELS; ++l)
        res.r[l] = (float)floor(16.0 * pow(growth, (double)l));

    const dim3 block(256, 1, 1);
    const dim3 grid(NPTS / 256, NLEVELS, 1);   // 4096 x 16

    HashGridEncoder_68925635166659_kernel<<<grid, block, 0, stream>>>(x, table, out, res);
}

// Round 2
// 848.244 us; speedup vs baseline: 1.0321x; 1.0321x over previous
//
#include <hip/hip_runtime.h>
#include <math.h>

#define NLEVELS 16
#define LOG2_T 19
#define TSIZE (1u << LOG2_T)
#define TMASK (TSIZE - 1u)
#define NPTS 1048576
#define HALFPTS (NPTS / 2)

typedef float vfloat2 __attribute__((ext_vector_type(2)));
typedef float vfloat4 __attribute__((ext_vector_type(4)));

struct Res16 { float r[NLEVELS]; };

// 2D grid: blockIdx.y = level, blockIdx.x = point block.
// Level phasing: dispatch is x-fastest, so each XCD's 4 MiB L2 holds the one
// active 4 MiB level slice (FETCH ~= the 8-XCD phased floor already).
//
// Round-2 change: 2 points per thread (n and n+HALFPTS, same level) to double
// per-thread memory-level parallelism (~13 independent vmem ops in flight vs 7).
// Counters showed latency-bound: 19% HBM BW, 5% VALU, ~4 cy per line-request.
// Also: x loads are now cached (no nontemporal) so the 12 MB x array stays
// L2/L3-resident across the 16 level phases instead of re-fetching from HBM.
__global__ __launch_bounds__(256) void HashGridEncoder_68925635166659_kernel(
    const float* __restrict__ x,
    const vfloat2* __restrict__ table,
    vfloat2* __restrict__ out,
    Res16 res)
{
    const int l = blockIdx.y;
    const int t = blockIdx.x * blockDim.x + threadIdx.x;
    const int nA = t;
    const int nB = t + HALFPTS;

    const float r = res.r[l];
    const vfloat2* __restrict__ tl  = table + (uint32_t)l * TSIZE;
    const vfloat4* __restrict__ tl4 = (const vfloat4*)tl;   // aligned entry pairs

    // x loads: plain (cached) loads; wave-contiguous, ~12 lines per instr.
    const float pxA = x[3 * nA + 0];
    const float pyA = x[3 * nA + 1];
    const float pzA = x[3 * nA + 2];
    const float pxB = x[3 * nB + 0];
    const float pyB = x[3 * nB + 1];
    const float pzB = x[3 * nB + 2];

    // ---- point A: exact reference f32 ops (mul, floor, sub) ----
    const float sxA = pxA * r, syA = pyA * r, szA = pzA * r;
    const float fxA = floorf(sxA), fyA = floorf(syA), fzA = floorf(szA);
    const float wxA = sxA - fxA, wyA = syA - fyA, wzA = szA - fzA;
    const uint32_t ixA = (uint32_t)(int)fxA;
    const uint32_t iyA = (uint32_t)(int)fyA;
    const uint32_t izA = (uint32_t)(int)fzA;
    const uint32_t hxA0 = ixA;                        // P1 = 1
    const uint32_t hxA1 = ixA + 1u;
    const uint32_t hyA0 = iyA * 2654435761u;
    const uint32_t hyA1 = hyA0 + 2654435761u;
    const uint32_t hzA0 = izA * 805459861u;
    const uint32_t hzA1 = hzA0 + 805459861u;
    const uint32_t bA00 = (hxA0 ^ hyA0 ^ hzA0) & TMASK;
    const uint32_t bA01 = (hxA0 ^ hyA0 ^ hzA1) & TMASK;
    const uint32_t bA10 = (hxA0 ^ hyA1 ^ hzA0) & TMASK;
    const uint32_t bA11 = (hxA0 ^ hyA1 ^ hzA1) & TMASK;

    // ---- point B ----
    const float sxB = pxB * r, syB = pyB * r, szB = pzB * r;
    const float fxB = floorf(sxB), fyB = floorf(syB), fzB = floorf(szB);
    const float wxB = sxB - fxB, wyB = syB - fyB, wzB = szB - fzB;
    const uint32_t ixB = (uint32_t)(int)fxB;
    const uint32_t iyB = (uint32_t)(int)fyB;
    const uint32_t izB = (uint32_t)(int)fzB;
    const uint32_t hxB0 = ixB;
    const uint32_t hxB1 = ixB + 1u;
    const uint32_t hyB0 = iyB * 2654435761u;
    const uint32_t hyB1 = hyB0 + 2654435761u;
    const uint32_t hzB0 = izB * 805459861u;
    const uint32_t hzB1 = hzB0 + 805459861u;
    const uint32_t bB00 = (hxB0 ^ hyB0 ^ hzB0) & TMASK;
    const uint32_t bB01 = (hxB0 ^ hyB0 ^ hzB1) & TMASK;
    const uint32_t bB10 = (hxB0 ^ hyB1 ^ hzB0) & TMASK;
    const uint32_t bB11 = (hxB0 ^ hyB1 ^ hzB1) & TMASK;

    // ---- issue all 8 quad gathers (independent, in flight together) ----
    const vfloat4 qA00 = tl4[bA00 >> 1];
    const vfloat4 qA01 = tl4[bA01 >> 1];
    const vfloat4 qA10 = tl4[bA10 >> 1];
    const vfloat4 qA11 = tl4[bA11 >> 1];
    const vfloat4 qB00 = tl4[bB00 >> 1];
    const vfloat4 qB01 = tl4[bB01 >> 1];
    const vfloat4 qB10 = tl4[bB10 >> 1];
    const vfloat4 qB11 = tl4[bB11 >> 1];

    // dx=0 corner = half addressed by b; other half = dx=1 corner iff ix even.
    const vfloat2 cA000 = (bA00 & 1u) ? vfloat2{qA00.z, qA00.w} : vfloat2{qA00.x, qA00.y};
    const vfloat2 cA001 = (bA01 & 1u) ? vfloat2{qA01.z, qA01.w} : vfloat2{qA01.x, qA01.y};
    const vfloat2 cA010 = (bA10 & 1u) ? vfloat2{qA10.z, qA10.w} : vfloat2{qA10.x, qA10.y};
    const vfloat2 cA011 = (bA11 & 1u) ? vfloat2{qA11.z, qA11.w} : vfloat2{qA11.x, qA11.y};
    vfloat2 cA100 = (bA00 & 1u) ? vfloat2{qA00.x, qA00.y} : vfloat2{qA00.z, qA00.w};
    vfloat2 cA101 = (bA01 & 1u) ? vfloat2{qA01.x, qA01.y} : vfloat2{qA01.z, qA01.w};
    vfloat2 cA110 = (bA10 & 1u) ? vfloat2{qA10.x, qA10.y} : vfloat2{qA10.z, qA10.w};
    vfloat2 cA111 = (bA11 & 1u) ? vfloat2{qA11.x, qA11.y} : vfloat2{qA11.z, qA11.w};

    const vfloat2 cB000 = (bB00 & 1u) ? vfloat2{qB00.z, qB00.w} : vfloat2{qB00.x, qB00.y};
    const vfloat2 cB001 = (bB01 & 1u) ? vfloat2{qB01.z, qB01.w} : vfloat2{qB01.x, qB01.y};
    const vfloat2 cB010 = (bB10 & 1u) ? vfloat2{qB10.z, qB10.w} : vfloat2{qB10.x, qB10.y};
    const vfloat2 cB011 = (bB11 & 1u) ? vfloat2{qB11.z, qB11.w} : vfloat2{qB11.x, qB11.y};
    vfloat2 cB100 = (bB00 & 1u) ? vfloat2{qB00.x, qB00.y} : vfloat2{qB00.z, qB00.w};
    vfloat2 cB101 = (bB01 & 1u) ? vfloat2{qB01.x, qB01.y} : vfloat2{qB01.z, qB01.w};
    vfloat2 cB110 = (bB10 & 1u) ? vfloat2{qB10.x, qB10.y} : vfloat2{qB10.z, qB10.w};
    vfloat2 cB111 = (bB11 & 1u) ? vfloat2{qB11.x, qB11.y} : vfloat2{qB11.z, qB11.w};

    // Odd-ix fallback gathers (exec-masked; ~half the lanes each).
    if (ixA & 1u) {
        cA100 = tl[(hxA1 ^ hyA0 ^ hzA0) & TMASK];
        cA101 = tl[(hxA1 ^ hyA0 ^ hzA1) & TMASK];
        cA110 = tl[(hxA1 ^ hyA1 ^ hzA0) & TMASK];
        cA111 = tl[(hxA1 ^ hyA1 ^ hzA1) & TMASK];
    }
    if (ixB & 1u) {
        cB100 = tl[(hxB1 ^ hyB0 ^ hzB0) & TMASK];
        cB101 = tl[(hxB1 ^ hyB0 ^ hzB1) & TMASK];
        cB110 = tl[(hxB1 ^ hyB1 ^ hzB0) & TMASK];
        cB111 = tl[(hxB1 ^ hyB1 ^ hzB1) & TMASK];
    }

    // ---- weighted accumulation, same corner order as reference ----
    {
        const float wx0 = 1.0f - wxA, wy0 = 1.0f - wyA, wz0 = 1.0f - wzA;
        float f0 = 0.0f, f1 = 0.0f, w;
        w = (wx0 * wy0) * wz0; f0 += cA000.x * w; f1 += cA000.y * w;
        w = (wx0 * wy0) * wzA; f0 += cA001.x * w; f1 += cA001.y * w;
        w = (wx0 * wyA) * wz0; f0 += cA010.x * w; f1 += cA010.y * w;
        w = (wx0 * wyA) * wzA; f0 += cA011.x * w; f1 += cA011.y * w;
        w = (wxA * wy0) * wz0; f0 += cA100.x * w; f1 += cA100.y * w;
        w = (wxA * wy0) * wzA; f0 += cA101.x * w; f1 += cA101.y * w;
        w = (wxA * wyA) * wz0; f0 += cA110.x * w; f1 += cA110.y * w;
        w = (wxA * wyA) * wzA; f0 += cA111.x * w; f1 += cA111.y * w;
        vfloat2 v; v.x = f0; v.y = f1;
        __builtin_nontemporal_store(v, out + (uint32_t)nA * NLEVELS + (uint32_t)l);
    }
    {
        const float wx0 = 1.0f - wxB, wy0 = 1.0f - wyB, wz0 = 1.0f - wzB;
        float f0 = 0.0f, f1 = 0.0f, w;
        w = (wx0 * wy0) * wz0; f0 += cB000.x * w; f1 += cB000.y * w;
        w = (wx0 * wy0) * wzB; f0 += cB001.x * w; f1 += cB001.y * w;
        w = (wx0 * wyB) * wz0; f0 += cB010.x * w; f1 += cB010.y * w;
        w = (wx0 * wyB) * wzB; f0 += cB011.x * w; f1 += cB011.y * w;
        w = (wxB * wy0) * wz0; f0 += cB100.x * w; f1 += cB100.y * w;
        w = (wxB * wy0) * wzB; f0 += cB101.x * w; f1 += cB101.y * w;
        w = (wxB * wyB) * wz0; f0 += cB110.x * w; f1 += cB110.y * w;
        w = (wxB * wyB) * wzB; f0 += cB111.x * w; f1 += cB111.y * w;
        vfloat2 v; v.x = f0; v.y = f1;
        __builtin_nontemporal_store(v, out + (uint32_t)nB * NLEVELS + (uint32_t)l);
    }
}

extern "C" void kernel_launch(void* const* d_in, const int* in_sizes, int n_in,
                              void* d_out, int out_size, void* d_ws, size_t ws_size,
                              hipStream_t stream) {
    const float*   x     = (const float*)d_in[0];
    const vfloat2* table = (const vfloat2*)d_in[1];
    vfloat2*       out   = (vfloat2*)d_out;

    // Exact numpy recipe in double: floor(16 * growth^l), growth = exp(ln(256)/15)
    Res16 res;
    const double growth = exp((log(4096.0) - log(16.0)) / 15.0);
    for (int l = 0; l < NLEVELS; ++l)
        res.r[l] = (float)floor(16.0 * pow(growth, (double)l));

    const dim3 block(256, 1, 1);
    const dim3 grid(HALFPTS / 256, NLEVELS, 1);   // 2048 x 16, 2 pts/thread

    HashGridEncoder_68925635166659_kernel<<<grid, block, 0, stream>>>(x, table, out, res);
}

// Round 3
// 762.097 us; speedup vs baseline: 1.1488x; 1.1130x over previous
//
#include <hip/hip_runtime.h>
#include <math.h>

#define NLEVELS 16
#define LOG2_T 19
#define TSIZE (1u << LOG2_T)
#define TMASK (TSIZE - 1u)
#define NPTS 1048576
#define HALFPTS (NPTS / 2)

typedef float vfloat2 __attribute__((ext_vector_type(2)));
typedef float vfloat4 __attribute__((ext_vector_type(4)));

struct Res16 { float r[NLEVELS]; };

// Main kernel. 2D grid: blockIdx.y = level, blockIdx.x = point block.
// Level phasing: dispatch is x-fastest, so each XCD's 4 MiB L2 holds the one
// active 4 MiB level slice.
//
// Round-3 changes:
//  * Branchless corner loads: c1 (dx=1) gathers issued UNCONDITIONALLY at the
//    true index (hx1^hy^hz)&MASK. For even ix this equals b^1 -> same 64 B line
//    as the quad just loaded (L1 hit, no extra L2 request); for odd ix it's the
//    real second gather. Removes both exec-branches AND the waitcnt-serialized
//    two-phase load structure: all 16 table loads per point-pair are independent
//    and in flight together.
//  * Stores go to ws[l][n] (coalesced, 8 lines/wave instead of 64); a second
//    tiny kernel transposes ws[16][N] -> out[N][16] fully coalesced.
//    mn/ml generalize the store index so the same kernel works direct (fallback).
__global__ __launch_bounds__(256) void HashGridEncoder_68925635166659_kernel(
    const float* __restrict__ x,
    const vfloat2* __restrict__ table,
    vfloat2* __restrict__ dst,
    const uint32_t mn, const uint32_t ml,   // store index = n*mn + l*ml
    Res16 res)
{
    const int l = blockIdx.y;
    const int t = blockIdx.x * blockDim.x + threadIdx.x;
    const int nA = t;
    const int nB = t + HALFPTS;

    const float r = res.r[l];
    const vfloat2* __restrict__ tl  = table + (uint32_t)l * TSIZE;
    const vfloat4* __restrict__ tl4 = (const vfloat4*)tl;   // aligned entry pairs

    const float pxA = x[3 * nA + 0];
    const float pyA = x[3 * nA + 1];
    const float pzA = x[3 * nA + 2];
    const float pxB = x[3 * nB + 0];
    const float pyB = x[3 * nB + 1];
    const float pzB = x[3 * nB + 2];

    // ---- point A: exact reference f32 ops (mul, floor, sub) ----
    const float sxA = pxA * r, syA = pyA * r, szA = pzA * r;
    const float fxA = floorf(sxA), fyA = floorf(syA), fzA = floorf(szA);
    const float wxA = sxA - fxA, wyA = syA - fyA, wzA = szA - fzA;
    const uint32_t ixA = (uint32_t)(int)fxA;
    const uint32_t iyA = (uint32_t)(int)fyA;
    const uint32_t izA = (uint32_t)(int)fzA;
    const uint32_t hxA1 = ixA + 1u;                   // P1 = 1
    const uint32_t hyA0 = iyA * 2654435761u;
    const uint32_t hyA1 = hyA0 + 2654435761u;
    const uint32_t hzA0 = izA * 805459861u;
    const uint32_t hzA1 = hzA0 + 805459861u;
    const uint32_t bA00 = (ixA ^ hyA0 ^ hzA0) & TMASK;
    const uint32_t bA01 = (ixA ^ hyA0 ^ hzA1) & TMASK;
    const uint32_t bA10 = (ixA ^ hyA1 ^ hzA0) & TMASK;
    const uint32_t bA11 = (ixA ^ hyA1 ^ hzA1) & TMASK;
    const uint32_t eA00 = (hxA1 ^ hyA0 ^ hzA0) & TMASK;  // dx=1 indices
    const uint32_t eA01 = (hxA1 ^ hyA0 ^ hzA1) & TMASK;
    const uint32_t eA10 = (hxA1 ^ hyA1 ^ hzA0) & TMASK;
    const uint32_t eA11 = (hxA1 ^ hyA1 ^ hzA1) & TMASK;

    // ---- point B ----
    const float sxB = pxB * r, syB = pyB * r, szB = pzB * r;
    const float fxB = floorf(sxB), fyB = floorf(syB), fzB = floorf(szB);
    const float wxB = sxB - fxB, wyB = syB - fyB, wzB = szB - fzB;
    const uint32_t ixB = (uint32_t)(int)fxB;
    const uint32_t iyB = (uint32_t)(int)fyB;
    const uint32_t izB = (uint32_t)(int)fzB;
    const uint32_t hxB1 = ixB + 1u;
    const uint32_t hyB0 = iyB * 2654435761u;
    const uint32_t hyB1 = hyB0 + 2654435761u;
    const uint32_t hzB0 = izB * 805459861u;
    const uint32_t hzB1 = hzB0 + 805459861u;
    const uint32_t bB00 = (ixB ^ hyB0 ^ hzB0) & TMASK;
    const uint32_t bB01 = (ixB ^ hyB0 ^ hzB1) & TMASK;
    const uint32_t bB10 = (ixB ^ hyB1 ^ hzB0) & TMASK;
    const uint32_t bB11 = (ixB ^ hyB1 ^ hzB1) & TMASK;
    const uint32_t eB00 = (hxB1 ^ hyB0 ^ hzB0) & TMASK;
    const uint32_t eB01 = (hxB1 ^ hyB0 ^ hzB1) & TMASK;
    const uint32_t eB10 = (hxB1 ^ hyB1 ^ hzB0) & TMASK;
    const uint32_t eB11 = (hxB1 ^ hyB1 ^ hzB1) & TMASK;

    // ---- all 16 table loads, independent, in flight together ----
    const vfloat4 qA00 = tl4[bA00 >> 1];
    const vfloat4 qA01 = tl4[bA01 >> 1];
    const vfloat4 qA10 = tl4[bA10 >> 1];
    const vfloat4 qA11 = tl4[bA11 >> 1];
    const vfloat2 cA100 = tl[eA00];
    const vfloat2 cA101 = tl[eA01];
    const vfloat2 cA110 = tl[eA10];
    const vfloat2 cA111 = tl[eA11];
    const vfloat4 qB00 = tl4[bB00 >> 1];
    const vfloat4 qB01 = tl4[bB01 >> 1];
    const vfloat4 qB10 = tl4[bB10 >> 1];
    const vfloat4 qB11 = tl4[bB11 >> 1];
    const vfloat2 cB100 = tl[eB00];
    const vfloat2 cB101 = tl[eB01];
    const vfloat2 cB110 = tl[eB10];
    const vfloat2 cB111 = tl[eB11];

    // dx=0 corners from quad halves (select by stored-index bit0).
    const vfloat2 cA000 = (bA00 & 1u) ? vfloat2{qA00.z, qA00.w} : vfloat2{qA00.x, qA00.y};
    const vfloat2 cA001 = (bA01 & 1u) ? vfloat2{qA01.z, qA01.w} : vfloat2{qA01.x, qA01.y};
    const vfloat2 cA010 = (bA10 & 1u) ? vfloat2{qA10.z, qA10.w} : vfloat2{qA10.x, qA10.y};
    const vfloat2 cA011 = (bA11 & 1u) ? vfloat2{qA11.z, qA11.w} : vfloat2{qA11.x, qA11.y};
    const vfloat2 cB000 = (bB00 & 1u) ? vfloat2{qB00.z, qB00.w} : vfloat2{qB00.x, qB00.y};
    const vfloat2 cB001 = (bB01 & 1u) ? vfloat2{qB01.z, qB01.w} : vfloat2{qB01.x, qB01.y};
    const vfloat2 cB010 = (bB10 & 1u) ? vfloat2{qB10.z, qB10.w} : vfloat2{qB10.x, qB10.y};
    const vfloat2 cB011 = (bB11 & 1u) ? vfloat2{qB11.z, qB11.w} : vfloat2{qB11.x, qB11.y};

    // ---- weighted accumulation, same corner order as reference ----
    {
        const float wx0 = 1.0f - wxA, wy0 = 1.0f - wyA, wz0 = 1.0f - wzA;
        float f0 = 0.0f, f1 = 0.0f, w;
        w = (wx0 * wy0) * wz0; f0 += cA000.x * w; f1 += cA000.y * w;
        w = (wx0 * wy0) * wzA; f0 += cA001.x * w; f1 += cA001.y * w;
        w = (wx0 * wyA) * wz0; f0 += cA010.x * w; f1 += cA010.y * w;
        w = (wx0 * wyA) * wzA; f0 += cA011.x * w; f1 += cA011.y * w;
        w = (wxA * wy0) * wz0; f0 += cA100.x * w; f1 += cA100.y * w;
        w = (wxA * wy0) * wzA; f0 += cA101.x * w; f1 += cA101.y * w;
        w = (wxA * wyA) * wz0; f0 += cA110.x * w; f1 += cA110.y * w;
        w = (wxA * wyA) * wzA; f0 += cA111.x * w; f1 += cA111.y * w;
        vfloat2 v; v.x = f0; v.y = f1;
        __builtin_nontemporal_store(v, dst + (uint32_t)nA * mn + (uint32_t)l * ml);
    }
    {
        const float wx0 = 1.0f - wxB, wy0 = 1.0f - wyB, wz0 = 1.0f - wzB;
        float f0 = 0.0f, f1 = 0.0f, w;
        w = (wx0 * wy0) * wz0; f0 += cB000.x * w; f1 += cB000.y * w;
        w = (wx0 * wy0) * wzB; f0 += cB001.x * w; f1 += cB001.y * w;
        w = (wx0 * wyB) * wz0; f0 += cB010.x * w; f1 += cB010.y * w;
        w = (wx0 * wyB) * wzB; f0 += cB011.x * w; f1 += cB011.y * w;
        w = (wxB * wy0) * wz0; f0 += cB100.x * w; f1 += cB100.y * w;
        w = (wxB * wy0) * wzB; f0 += cB101.x * w; f1 += cB101.y * w;
        w = (wxB * wyB) * wz0; f0 += cB110.x * w; f1 += cB110.y * w;
        w = (wxB * wyB) * wzB; f0 += cB111.x * w; f1 += cB111.y * w;
        vfloat2 v; v.x = f0; v.y = f1;
        __builtin_nontemporal_store(v, dst + (uint32_t)nB * mn + (uint32_t)l * ml);
    }
}

// Transpose ws[16][NPTS] -> out[NPTS][16], both sides coalesced via LDS tile.
// Block = 256 threads, 32 points. Write: lane i stores base + i*16 B (perfect).
__global__ __launch_bounds__(256) void HashGridEncoder_68925635166659_transpose(
    const vfloat2* __restrict__ ws,
    vfloat4* __restrict__ out4)
{
    __shared__ vfloat2 tile[NLEVELS][33];
    const int t  = threadIdx.x;
    const int p0 = blockIdx.x * 32;

    const int j  = t & 31;
    const int l0 = (t >> 5) * 2;           // 0,2,...,14 across the 8 half-waves
    tile[l0][j]     = ws[(uint32_t)l0       * NPTS + p0 + j];
    tile[l0 + 1][j] = ws[(uint32_t)(l0 + 1) * NPTS + p0 + j];
    __syncthreads();

    const int p = t >> 3;                  // 0..31
    const int c = t & 7;                   // 16 B chunk within the 128 B row
    const vfloat2 a = tile[2 * c][p];
    const vfloat2 b = tile[2 * c + 1][p];
    vfloat4 v; v.x = a.x; v.y = a.y; v.z = b.x; v.w = b.y;
    __builtin_nontemporal_store(v, out4 + (uint32_t)(p0 + p) * 8 + c);
}

extern "C" void kernel_launch(void* const* d_in, const int* in_sizes, int n_in,
                              void* d_out, int out_size, void* d_ws, size_t ws_size,
                              hipStream_t stream) {
    const float*   x     = (const float*)d_in[0];
    const vfloat2* table = (const vfloat2*)d_in[1];
    vfloat2*       out   = (vfloat2*)d_out;

    // Exact numpy recipe in double: floor(16 * growth^l), growth = exp(ln(256)/15)
    Res16 res;
    const double growth = exp((log(4096.0) - log(16.0)) / 15.0);
    for (int l = 0; l < NLEVELS; ++l)
        res.r[l] = (float)floor(16.0 * pow(growth, (double)l));

    const dim3 block(256, 1, 1);
    const dim3 grid(HALFPTS / 256, NLEVELS, 1);   // 2048 x 16, 2 pts/thread

    const size_t ws_needed = (size_t)NLEVELS * NPTS * sizeof(vfloat2);  // 128 MiB
    if (ws_size >= ws_needed && d_ws != nullptr) {
        vfloat2* ws = (vfloat2*)d_ws;
        // Coalesced store path: ws[l][n], then transpose to out[n][l].
        HashGridEncoder_68925635166659_kernel<<<grid, block, 0, stream>>>(
            x, table, ws, 1u, (uint32_t)NPTS, res);
        HashGridEncoder_68925635166659_transpose<<<dim3(NPTS / 32, 1, 1), block, 0, stream>>>(
            ws, (vfloat4*)out);
    } else {
        // Fallback: direct strided stores to out[n][l].
        HashGridEncoder_68925635166659_kernel<<<grid, block, 0, stream>>>(
            x, table, out, (uint32_t)NLEVELS, 1u, res);
    }
}

// Round 4
// 628.557 us; speedup vs baseline: 1.3928x; 1.2125x over previous
//
#include <hip/hip_runtime.h>
#include <math.h>

#define NLEVELS 16
#define LOG2_T 19
#define TSIZE (1u << LOG2_T)
#define TMASK (TSIZE - 1u)
#define NPTS 1048576
#define HALFPTS (NPTS / 2)

typedef float vfloat2 __attribute__((ext_vector_type(2)));
typedef float vfloat4 __attribute__((ext_vector_type(4)));

struct Res16 { float r[NLEVELS]; };

// Main kernel. 2D grid: blockIdx.y = level, blockIdx.x = point block.
// Level phasing: dispatch is x-fastest; all 2048 blocks of one level are
// co-resident, so each XCD's 4 MiB L2 holds the one active level slice.
//
// Round-4 change: dx=1 gathers are exec-masked to odd-ix lanes only (for even
// ix the dx=1 corner is the other half of the quad line -> select, no new
// address). Unlike round 1, the masked loads are issued BEFORE the quad loads
// (their predicate depends only on ix), so all table loads still belong to a
// single latency round. Cuts per-lane address slots / L1 tag lookups from 8
// to ~6 per point-level.
__global__ __launch_bounds__(256) void HashGridEncoder_68925635166659_kernel(
    const float* __restrict__ x,
    const vfloat2* __restrict__ table,
    vfloat2* __restrict__ dst,
    const uint32_t mn, const uint32_t ml,   // store index = n*mn + l*ml
    Res16 res)
{
    const int l = blockIdx.y;
    const int t = blockIdx.x * blockDim.x + threadIdx.x;
    const int nA = t;
    const int nB = t + HALFPTS;

    const float r = res.r[l];
    const vfloat2* __restrict__ tl  = table + (uint32_t)l * TSIZE;
    const vfloat4* __restrict__ tl4 = (const vfloat4*)tl;   // aligned entry pairs

    const float pxA = x[3 * nA + 0];
    const float pyA = x[3 * nA + 1];
    const float pzA = x[3 * nA + 2];
    const float pxB = x[3 * nB + 0];
    const float pyB = x[3 * nB + 1];
    const float pzB = x[3 * nB + 2];

    // ---- point A: exact reference f32 ops (mul, floor, sub) ----
    const float sxA = pxA * r, syA = pyA * r, szA = pzA * r;
    const float fxA = floorf(sxA), fyA = floorf(syA), fzA = floorf(szA);
    const float wxA = sxA - fxA, wyA = syA - fyA, wzA = szA - fzA;
    const uint32_t ixA = (uint32_t)(int)fxA;
    const uint32_t iyA = (uint32_t)(int)fyA;
    const uint32_t izA = (uint32_t)(int)fzA;
    const uint32_t hxA1 = ixA + 1u;                   // P1 = 1
    const uint32_t hyA0 = iyA * 2654435761u;
    const uint32_t hyA1 = hyA0 + 2654435761u;
    const uint32_t hzA0 = izA * 805459861u;
    const uint32_t hzA1 = hzA0 + 805459861u;
    const uint32_t bA00 = (ixA ^ hyA0 ^ hzA0) & TMASK;
    const uint32_t bA01 = (ixA ^ hyA0 ^ hzA1) & TMASK;
    const uint32_t bA10 = (ixA ^ hyA1 ^ hzA0) & TMASK;
    const uint32_t bA11 = (ixA ^ hyA1 ^ hzA1) & TMASK;
    const uint32_t eA00 = (hxA1 ^ hyA0 ^ hzA0) & TMASK;  // dx=1 indices
    const uint32_t eA01 = (hxA1 ^ hyA0 ^ hzA1) & TMASK;
    const uint32_t eA10 = (hxA1 ^ hyA1 ^ hzA0) & TMASK;
    const uint32_t eA11 = (hxA1 ^ hyA1 ^ hzA1) & TMASK;

    // ---- point B ----
    const float sxB = pxB * r, syB = pyB * r, szB = pzB * r;
    const float fxB = floorf(sxB), fyB = floorf(syB), fzB = floorf(szB);
    const float wxB = sxB - fxB, wyB = syB - fyB, wzB = szB - fzB;
    const uint32_t ixB = (uint32_t)(int)fxB;
    const uint32_t iyB = (uint32_t)(int)fyB;
    const uint32_t izB = (uint32_t)(int)fzB;
    const uint32_t hxB1 = ixB + 1u;
    const uint32_t hyB0 = iyB * 2654435761u;
    const uint32_t hyB1 = hyB0 + 2654435761u;
    const uint32_t hzB0 = izB * 805459861u;
    const uint32_t hzB1 = hzB0 + 805459861u;
    const uint32_t bB00 = (ixB ^ hyB0 ^ hzB0) & TMASK;
    const uint32_t bB01 = (ixB ^ hyB0 ^ hzB1) & TMASK;
    const uint32_t bB10 = (ixB ^ hyB1 ^ hzB0) & TMASK;
    const uint32_t bB11 = (ixB ^ hyB1 ^ hzB1) & TMASK;
    const uint32_t eB00 = (hxB1 ^ hyB0 ^ hzB0) & TMASK;
    const uint32_t eB01 = (hxB1 ^ hyB0 ^ hzB1) & TMASK;
    const uint32_t eB10 = (hxB1 ^ hyB1 ^ hzB0) & TMASK;
    const uint32_t eB11 = (hxB1 ^ hyB1 ^ hzB1) & TMASK;

    // ---- masked dx=1 gathers FIRST (predicate depends only on ix) ----
    vfloat2 cA100, cA101, cA110, cA111;
    vfloat2 cB100, cB101, cB110, cB111;
    const uint32_t oddA = ixA & 1u;
    const uint32_t oddB = ixB & 1u;
    if (oddA) {
        cA100 = tl[eA00];
        cA101 = tl[eA01];
        cA110 = tl[eA10];
        cA111 = tl[eA11];
    }
    if (oddB) {
        cB100 = tl[eB00];
        cB101 = tl[eB01];
        cB110 = tl[eB10];
        cB111 = tl[eB11];
    }

    // ---- 8 quad loads, independent, same latency round ----
    const vfloat4 qA00 = tl4[bA00 >> 1];
    const vfloat4 qA01 = tl4[bA01 >> 1];
    const vfloat4 qA10 = tl4[bA10 >> 1];
    const vfloat4 qA11 = tl4[bA11 >> 1];
    const vfloat4 qB00 = tl4[bB00 >> 1];
    const vfloat4 qB01 = tl4[bB01 >> 1];
    const vfloat4 qB10 = tl4[bB10 >> 1];
    const vfloat4 qB11 = tl4[bB11 >> 1];

    // dx=0 corners = quad half addressed by b (select by stored-index bit0).
    const vfloat2 cA000 = (bA00 & 1u) ? vfloat2{qA00.z, qA00.w} : vfloat2{qA00.x, qA00.y};
    const vfloat2 cA001 = (bA01 & 1u) ? vfloat2{qA01.z, qA01.w} : vfloat2{qA01.x, qA01.y};
    const vfloat2 cA010 = (bA10 & 1u) ? vfloat2{qA10.z, qA10.w} : vfloat2{qA10.x, qA10.y};
    const vfloat2 cA011 = (bA11 & 1u) ? vfloat2{qA11.z, qA11.w} : vfloat2{qA11.x, qA11.y};
    const vfloat2 cB000 = (bB00 & 1u) ? vfloat2{qB00.z, qB00.w} : vfloat2{qB00.x, qB00.y};
    const vfloat2 cB001 = (bB01 & 1u) ? vfloat2{qB01.z, qB01.w} : vfloat2{qB01.x, qB01.y};
    const vfloat2 cB010 = (bB10 & 1u) ? vfloat2{qB10.z, qB10.w} : vfloat2{qB10.x, qB10.y};
    const vfloat2 cB011 = (bB11 & 1u) ? vfloat2{qB11.z, qB11.w} : vfloat2{qB11.x, qB11.y};

    // dx=1 corners for even-ix lanes = the OTHER quad half.
    if (!oddA) {
        cA100 = (bA00 & 1u) ? vfloat2{qA00.x, qA00.y} : vfloat2{qA00.z, qA00.w};
        cA101 = (bA01 & 1u) ? vfloat2{qA01.x, qA01.y} : vfloat2{qA01.z, qA01.w};
        cA110 = (bA10 & 1u) ? vfloat2{qA10.x, qA10.y} : vfloat2{qA10.z, qA10.w};
        cA111 = (bA11 & 1u) ? vfloat2{qA11.x, qA11.y} : vfloat2{qA11.z, qA11.w};
    }
    if (!oddB) {
        cB100 = (bB00 & 1u) ? vfloat2{qB00.x, qB00.y} : vfloat2{qB00.z, qB00.w};
        cB101 = (bB01 & 1u) ? vfloat2{qB01.x, qB01.y} : vfloat2{qB01.z, qB01.w};
        cB110 = (bB10 & 1u) ? vfloat2{qB10.x, qB10.y} : vfloat2{qB10.z, qB10.w};
        cB111 = (bB11 & 1u) ? vfloat2{qB11.x, qB11.y} : vfloat2{qB11.z, qB11.w};
    }

    // ---- weighted accumulation, same corner order as reference ----
    {
        const float wx0 = 1.0f - wxA, wy0 = 1.0f - wyA, wz0 = 1.0f - wzA;
        float f0 = 0.0f, f1 = 0.0f, w;
        w = (wx0 * wy0) * wz0; f0 += cA000.x * w; f1 += cA000.y * w;
        w = (wx0 * wy0) * wzA; f0 += cA001.x * w; f1 += cA001.y * w;
        w = (wx0 * wyA) * wz0; f0 += cA010.x * w; f1 += cA010.y * w;
        w = (wx0 * wyA) * wzA; f0 += cA011.x * w; f1 += cA011.y * w;
        w = (wxA * wy0) * wz0; f0 += cA100.x * w; f1 += cA100.y * w;
        w = (wxA * wy0) * wzA; f0 += cA101.x * w; f1 += cA101.y * w;
        w = (wxA * wyA) * wz0; f0 += cA110.x * w; f1 += cA110.y * w;
        w = (wxA * wyA) * wzA; f0 += cA111.x * w; f1 += cA111.y * w;
        vfloat2 v; v.x = f0; v.y = f1;
        __builtin_nontemporal_store(v, dst + (uint32_t)nA * mn + (uint32_t)l * ml);
    }
    {
        const float wx0 = 1.0f - wxB, wy0 = 1.0f - wyB, wz0 = 1.0f - wzB;
        float f0 = 0.0f, f1 = 0.0f, w;
        w = (wx0 * wy0) * wz0; f0 += cB000.x * w; f1 += cB000.y * w;
        w = (wx0 * wy0) * wzB; f0 += cB001.x * w; f1 += cB001.y * w;
        w = (wx0 * wyB) * wz0; f0 += cB010.x * w; f1 += cB010.y * w;
        w = (wx0 * wyB) * wzB; f0 += cB011.x * w; f1 += cB011.y * w;
        w = (wxB * wy0) * wz0; f0 += cB100.x * w; f1 += cB100.y * w;
        w = (wxB * wy0) * wzB; f0 += cB101.x * w; f1 += cB101.y * w;
        w = (wxB * wyB) * wz0; f0 += cB110.x * w; f1 += cB110.y * w;
        w = (wxB * wyB) * wzB; f0 += cB111.x * w; f1 += cB111.y * w;
        vfloat2 v; v.x = f0; v.y = f1;
        __builtin_nontemporal_store(v, dst + (uint32_t)nB * mn + (uint32_t)l * ml);
    }
}

// Transpose ws[16][NPTS] -> out[NPTS][16]. 256-point tiles, vfloat4 both sides.
// Per block: 16 KB in + 16 KB out (vs 4 KB in round 3 -> launch-bound).
// LDS row stride padded to 258 vfloat2 (2064 B, 16 B-aligned): b128 tile writes
// contiguous per wave (conflict-free), b64 transposed reads 2-way (free).
__global__ __launch_bounds__(256) void HashGridEncoder_68925635166659_transpose(
    const vfloat2* __restrict__ ws,
    vfloat4* __restrict__ out4)
{
    __shared__ vfloat2 tile[NLEVELS][258];
    const int t  = threadIdx.x;
    const int p0 = blockIdx.x * 256;

    const vfloat4* __restrict__ ws4 = (const vfloat4*)ws;
    #pragma unroll
    for (int k = 0; k < 8; ++k) {
        const int lin = k * 256 + t;        // 0..2047 over [16][128] vfloat4
        const int row = lin >> 7;
        const int col = lin & 127;
        const vfloat4 v = __builtin_nontemporal_load(
            ws4 + (size_t)row * (NPTS / 2) + (p0 >> 1) + col);
        *(vfloat4*)&tile[row][2 * col] = v;   // 16B-aligned (p0 even, stride 258)
    }
    __syncthreads();
    #pragma unroll
    for (int k = 0; k < 8; ++k) {
        const int lin = k * 256 + t;        // 0..2047 over [256 pts][8 chunks]
        const int p = lin >> 3;
        const int c = lin & 7;
        const vfloat2 a = tile[2 * c][p];
        const vfloat2 b = tile[2 * c + 1][p];
        vfloat4 v; v.x = a.x; v.y = a.y; v.z = b.x; v.w = b.y;
        __builtin_nontemporal_store(v, out4 + (size_t)(p0 + p) * 8 + c);
    }
}

extern "C" void kernel_launch(void* const* d_in, const int* in_sizes, int n_in,
                              void* d_out, int out_size, void* d_ws, size_t ws_size,
                              hipStream_t stream) {
    const float*   x     = (const float*)d_in[0];
    const vfloat2* table = (const vfloat2*)d_in[1];
    vfloat2*       out   = (vfloat2*)d_out;

    // Exact numpy recipe in double: floor(16 * growth^l), growth = exp(ln(256)/15)
    Res16 res;
    const double growth = exp((log(4096.0) - log(16.0)) / 15.0);
    for (int l = 0; l < NLEVELS; ++l)
        res.r[l] = (float)floor(16.0 * pow(growth, (double)l));

    const dim3 block(256, 1, 1);
    const dim3 grid(HALFPTS / 256, NLEVELS, 1);   // 2048 x 16, 2 pts/thread

    const size_t ws_needed = (size_t)NLEVELS * NPTS * sizeof(vfloat2);  // 128 MiB
    if (ws_size >= ws_needed && d_ws != nullptr) {
        vfloat2* ws = (vfloat2*)d_ws;
        HashGridEncoder_68925635166659_kernel<<<grid, block, 0, stream>>>(
            x, table, ws, 1u, (uint32_t)NPTS, res);
        HashGridEncoder_68925635166659_transpose<<<dim3(NPTS / 256, 1, 1), block, 0, stream>>>(
            ws, (vfloat4*)out);
    } else {
        HashGridEncoder_68925635166659_kernel<<<grid, block, 0, stream>>>(
            x, table, out, (uint32_t)NLEVELS, 1u, res);
    }
}